// Round 2
// baseline (107427.954 us; speedup 1.0000x reference)
//
#include <hip/hip_runtime.h>
#include <math.h>

// LSTM autoencoder, fp32. Single persistent kernel, weights LDS-resident.
// B=128, T=512, H=256. 512 blocks = 8 batch-groups(16 batch) x 64 hidden-groups(4 hidden).
// Thread layout: kq(16 K-split) x j(4 hidden) x bp(4 wave=4 batches); each thread
// accumulates 4 gates x 4 batches; ownership-splitting butterfly reduce leaves each
// lane with the 4 gates of one (j, batch). c-state in registers for the whole kernel.
// 2 monotone-counter group barriers per step (64 blocks/group).

#define B_    128
#define T_    512
#define H_    256
#define G_    1024          // 4*H
#define BB    16            // batch per group
#define NBG   8             // batch groups (blockIdx & 7 -> XCD round-robin heuristic)
#define JJ    4             // hidden units per block
#define NHG   64            // hidden-group blocks per batch group
#define NBLK  (NBG*NHG)     // 512 blocks, 2/CU co-resident (LDS 50KB, launch_bounds(256,2))
#define NTHR  256
#define WROW  16            // gate rows per block (4 gates * JJ)
#define WPAD  260           // LDS row stride (floats); 260%8==4 -> uniform bank spread

// ws float offsets
#define WS_H0   0                         // [2][B][H] double-buffered h0
#define WS_H1   (WS_H0 + 2*B_*H_)         // [2][B][H]
#define WS_EB   (WS_H1 + 2*B_*H_)         // [4][G]: enc0, enc1, dec0, dec1 combined biases
#define WS_BAR  (WS_EB + 4*G_)            // NBG monotone counters, stride 64 ints

__global__ void init_kernel(float* __restrict__ ws,
    const float* __restrict__ e0a, const float* __restrict__ e0b,
    const float* __restrict__ e1a, const float* __restrict__ e1b,
    const float* __restrict__ d0a, const float* __restrict__ d0b,
    const float* __restrict__ d1a, const float* __restrict__ d1b)
{
  int i = blockIdx.x*blockDim.x + threadIdx.x;
  int n = gridDim.x*blockDim.x;
  for (int k = i; k < 4*B_*H_; k += n) ws[WS_H0 + k] = 0.0f;  // h0,h1 both parities
  for (int k = i; k < G_; k += n) {
    ws[WS_EB + 0*G_ + k] = e0a[k] + e0b[k];
    ws[WS_EB + 1*G_ + k] = e1a[k] + e1b[k];
    ws[WS_EB + 2*G_ + k] = d0a[k] + d0b[k];
    ws[WS_EB + 3*G_ + k] = d1a[k] + d1b[k];
  }
  int* bar = (int*)(ws + WS_BAR);
  for (int k = i; k < NBG*64; k += n) bar[k] = 0;
}

__device__ __forceinline__ float sigm(float v) { return 1.0f/(1.0f + expf(-v)); }

// stage a 16-row x 256-col weight slice into LDS (once per segment, coalesced)
__device__ __forceinline__ void stage16(float* dst, const float* __restrict__ W,
                                        int j0, int tid)
{
#pragma unroll
  for (int m = 0; m < 4; ++m) {
    int idx = tid + m*NTHR;              // float4 index, 1024 total
    int r   = idx >> 6;                  // 0..15 local row
    int c4  = idx & 63;
    int grow = (r >> 2)*H_ + j0 + (r & 3);
    float4 v = *(const float4*)(W + grow*H_ + c4*4);
    *(float4*)(dst + r*WPAD + c4*4) = v;
  }
}

// r[i*4+q] += W[q*4+j] . h[bp*4+i] over this lane's K-sixteenth (interleaved chunks)
__device__ __forceinline__ void dot16(float r[16], const float* __restrict__ wlds,
                                      const float* __restrict__ hgrp,
                                      int j, int bp, int kq)
{
#pragma unroll
  for (int m = 0; m < 4; ++m) {
    const int ko = kq*4 + m*64;
    float4 hv[4], wv[4];
#pragma unroll
    for (int i = 0; i < 4; ++i)
      hv[i] = *(const float4*)(hgrp + (bp*4 + i)*H_ + ko);
#pragma unroll
    for (int q = 0; q < 4; ++q)
      wv[q] = *(const float4*)(wlds + (q*4 + j)*WPAD + ko);
#pragma unroll
    for (int i = 0; i < 4; ++i)
#pragma unroll
      for (int q = 0; q < 4; ++q)
        r[i*4+q] += wv[q].x*hv[i].x + wv[q].y*hv[i].y
                  + wv[q].z*hv[i].z + wv[q].w*hv[i].w;
  }
}

// ownership-splitting butterfly over the 16 kq lanes:
// after this, lane kq holds r[0..3] = gates q=0..3 of batch i_own = kq>>2
__device__ __forceinline__ void reduce16(float r[16], int kq)
{
  {
    bool hi = (kq & 8) != 0;
#pragma unroll
    for (int v = 0; v < 8; ++v) {
      float keep = hi ? r[v+8] : r[v];
      float send = hi ? r[v] : r[v+8];
      r[v] = keep + __shfl_xor(send, 8);
    }
  }
  {
    bool hi = (kq & 4) != 0;
#pragma unroll
    for (int v = 0; v < 4; ++v) {
      float keep = hi ? r[v+4] : r[v];
      float send = hi ? r[v] : r[v+4];
      r[v] = keep + __shfl_xor(send, 4);
    }
  }
#pragma unroll
  for (int v = 0; v < 4; ++v) {
    r[v] += __shfl_xor(r[v], 2);
    r[v] += __shfl_xor(r[v], 1);
  }
}

// monotone-counter group barrier: arrivals accumulate; barrier k waits for NHG*(k+1)
__device__ __forceinline__ void bg_barrier(int* cnt, int ph)
{
  __syncthreads();                       // all waves' stores drained (vmcnt) & reads done
  if (threadIdx.x == 0) {
    __threadfence();                     // release: L2 writeback to coherent point
    __hip_atomic_fetch_add(cnt, 1, __ATOMIC_RELEASE, __HIP_MEMORY_SCOPE_AGENT);
    const int target = NHG*(ph + 1);
    while (__hip_atomic_load(cnt, __ATOMIC_RELAXED, __HIP_MEMORY_SCOPE_AGENT) < target)
      __builtin_amdgcn_s_sleep(2);
  }
  __syncthreads();
  __threadfence();                       // acquire: invalidate stale L1/L2 before h reads
}

template<bool DEC>
__device__ __forceinline__ void run_seg(
    float* __restrict__ h0g, float* __restrict__ h1g,
    const float* __restrict__ x, float* __restrict__ dout,
    const float* wA, const float* wB, const float* wC, float* slds,
    int* cnt, int& ph,
    const float (&ebA)[4], const float (&ebB)[4], const float (&w0v)[4],
    const float4 (&outwv)[4], float outb,
    int kq, int j, int bp, int j0, int bgb, int b_own, int hg,
    float& c0, float& c1)
{
  for (int t = 0; t < T_; ++t) {
    const int rp = t & 1, wp = rp ^ 1;

    float inp;
    if (DEC) {
      if (t == 0) {
        inp = x[b_own*T_];                       // init_inp = x[:,0]
      } else {
        // out(t-1) = outW . h1(t-1) + outb ; doubles as this step's input
        const int s = threadIdx.x & 15, bo = threadIdx.x >> 4;
        const float* hp = h1g + rp*B_*H_ + (bgb + bo)*H_ + s*16;
        float a = 0.f;
#pragma unroll
        for (int u = 0; u < 4; ++u) {
          float4 hv = *(const float4*)(hp + u*4);
          a += outwv[u].x*hv.x + outwv[u].y*hv.y + outwv[u].z*hv.z + outwv[u].w*hv.w;
        }
        a += __shfl_xor(a, 8); a += __shfl_xor(a, 4);
        a += __shfl_xor(a, 2); a += __shfl_xor(a, 1);
        if (s == 0) {
          float o = a + outb;
          slds[bo] = o;
          if (hg == 0) dout[(bgb + bo)*T_ + (t-1)] = o;
        }
        __syncthreads();
        inp = slds[bp*4 + (kq >> 2)];
      }
    } else {
      inp = x[b_own*T_ + t];
    }

    // ---- phase A: layer 0 ----
    float r[16];
#pragma unroll
    for (int v = 0; v < 16; ++v) r[v] = 0.f;
    dot16(r, wA, h0g + rp*B_*H_ + bgb*H_, j, bp, kq);
    reduce16(r, kq);
    {
      float p0 = r[0] + ebA[0] + inp*w0v[0];
      float p1 = r[1] + ebA[1] + inp*w0v[1];
      float p2 = r[2] + ebA[2] + inp*w0v[2];
      float p3 = r[3] + ebA[3] + inp*w0v[3];
      float si = sigm(p0), sf = sigm(p1), tg = tanhf(p2), so = sigm(p3);
      c0 = sf*c0 + si*tg;
      float hv = so*tanhf(c0);
      if ((kq & 3) == 0) h0g[wp*B_*H_ + b_own*H_ + j0 + j] = hv;
    }
    bg_barrier(cnt, ph); ++ph;

    // ---- phase B: layer 1 (two dots share the accumulator) ----
#pragma unroll
    for (int v = 0; v < 16; ++v) r[v] = 0.f;
    dot16(r, wB, h0g + wp*B_*H_ + bgb*H_, j, bp, kq);   // Wih1 . h0(t)
    dot16(r, wC, h1g + rp*B_*H_ + bgb*H_, j, bp, kq);   // Whh1 . h1(t-1)
    reduce16(r, kq);
    {
      float p0 = r[0] + ebB[0];
      float p1 = r[1] + ebB[1];
      float p2 = r[2] + ebB[2];
      float p3 = r[3] + ebB[3];
      float si = sigm(p0), sf = sigm(p1), tg = tanhf(p2), so = sigm(p3);
      c1 = sf*c1 + si*tg;
      float hv = so*tanhf(c1);
      if ((kq & 3) == 0) h1g[wp*B_*H_ + b_own*H_ + j0 + j] = hv;
    }
    bg_barrier(cnt, ph); ++ph;
  }
}

__global__ __launch_bounds__(NTHR, 2) void lstm_fused(
    float* __restrict__ ws,
    const float* __restrict__ x,
    const float* __restrict__ eWih0, const float* __restrict__ eWhh0,
    const float* __restrict__ eWih1, const float* __restrict__ eWhh1,
    const float* __restrict__ dWih0, const float* __restrict__ dWhh0,
    const float* __restrict__ dWih1, const float* __restrict__ dWhh1,
    const float* __restrict__ outW,  const float* __restrict__ outB,
    float* __restrict__ dout)
{
  const int bg = blockIdx.x & (NBG-1);   // & 7: round-robin -> one group per XCD (heuristic)
  const int hg = blockIdx.x >> 3;        // 0..63
  const int tid = threadIdx.x;
  const int kq = tid & 15, j = (tid >> 4) & 3, bp = tid >> 6;
  const int j0 = hg*JJ, bgb = bg*BB;
  const int b_own = bgb + bp*4 + (kq >> 2);

  __shared__ __align__(16) float wA[WROW*WPAD];   // 16.6 KB each; 50 KB total
  __shared__ __align__(16) float wB[WROW*WPAD];
  __shared__ __align__(16) float wC[WROW*WPAD];
  __shared__ float slds[BB];

  float* h0g = ws + WS_H0;
  float* h1g = ws + WS_H1;
  const float* EB = ws + WS_EB;
  int* cnt = (int*)(ws + WS_BAR) + bg*64;

  // ---- encoder weights resident in LDS for all 512 steps ----
  stage16(wA, eWhh0, j0, tid);
  stage16(wB, eWih1, j0, tid);
  stage16(wC, eWhh1, j0, tid);

  float ebA[4], ebB[4], w0v[4];
#pragma unroll
  for (int q = 0; q < 4; ++q) {
    ebA[q] = EB[0*G_ + q*H_ + j0 + j];
    ebB[q] = EB[1*G_ + q*H_ + j0 + j];
    w0v[q] = eWih0[q*H_ + j0 + j];
  }
  float4 outwv[4];
#pragma unroll
  for (int u = 0; u < 4; ++u)
    outwv[u] = *(const float4*)(outW + (tid & 15)*16 + u*4);
  const float outb = outB[0];

  float c0 = 0.f, c1 = 0.f;
  int ph = 0;
  __syncthreads();

  run_seg<false>(h0g, h1g, x, dout, wA, wB, wC, slds, cnt, ph,
                 ebA, ebB, w0v, outwv, outb, kq, j, bp, j0, bgb, b_own, hg, c0, c1);

  // ---- enc->dec transition: restage weights; c0/c1 stay in registers ----
  stage16(wA, dWhh0, j0, tid);
  stage16(wB, dWih1, j0, tid);
  stage16(wC, dWhh1, j0, tid);
#pragma unroll
  for (int q = 0; q < 4; ++q) {
    ebA[q] = EB[2*G_ + q*H_ + j0 + j];
    ebB[q] = EB[3*G_ + q*H_ + j0 + j];
    w0v[q] = dWih0[q*H_ + j0 + j];
  }
  __syncthreads();

  run_seg<true>(h0g, h1g, x, dout, wA, wB, wC, slds, cnt, ph,
                ebA, ebB, w0v, outwv, outb, kq, j, bp, j0, bgb, b_own, hg, c0, c1);

  // ---- final output out(T-1) from h1(T-1) (parity 0 since T even) ----
  {
    const int s = tid & 15, bo = tid >> 4;
    const float* hp = h1g + (bgb + bo)*H_ + s*16;
    float a = 0.f;
#pragma unroll
    for (int u = 0; u < 4; ++u) {
      float4 hv = *(const float4*)(hp + u*4);
      a += outwv[u].x*hv.x + outwv[u].y*hv.y + outwv[u].z*hv.z + outwv[u].w*hv.w;
    }
    a += __shfl_xor(a, 8); a += __shfl_xor(a, 4);
    a += __shfl_xor(a, 2); a += __shfl_xor(a, 1);
    if (s == 0 && hg == 0) dout[(bgb + bo)*T_ + (T_-1)] = a + outb;
  }
}

extern "C" void kernel_launch(void* const* d_in, const int* in_sizes, int n_in,
                              void* d_out, int out_size, void* d_ws, size_t ws_size,
                              hipStream_t stream)
{
  const float* x     = (const float*)d_in[0];
  const float* eWih0 = (const float*)d_in[1];
  const float* eWhh0 = (const float*)d_in[2];
  const float* ebih0 = (const float*)d_in[3];
  const float* ebhh0 = (const float*)d_in[4];
  const float* eWih1 = (const float*)d_in[5];
  const float* eWhh1 = (const float*)d_in[6];
  const float* ebih1 = (const float*)d_in[7];
  const float* ebhh1 = (const float*)d_in[8];
  const float* dWih0 = (const float*)d_in[9];
  const float* dWhh0 = (const float*)d_in[10];
  const float* dbih0 = (const float*)d_in[11];
  const float* dbhh0 = (const float*)d_in[12];
  const float* dWih1 = (const float*)d_in[13];
  const float* dWhh1 = (const float*)d_in[14];
  const float* dbih1 = (const float*)d_in[15];
  const float* dbhh1 = (const float*)d_in[16];
  const float* outW  = (const float*)d_in[17];
  const float* outB  = (const float*)d_in[18];
  float* out = (float*)d_out;
  float* ws  = (float*)d_ws;

  init_kernel<<<dim3(64), dim3(256), 0, stream>>>(ws, ebih0, ebhh0, ebih1, ebhh1,
                                                  dbih0, dbhh0, dbih1, dbhh1);
  lstm_fused<<<dim3(NBLK), dim3(NTHR), 0, stream>>>(
      ws, x, eWih0, eWhh0, eWih1, eWhh1,
      dWih0, dWhh0, dWih1, dWhh1, outW, outB, out);
}

// Round 11
// 9732.310 us; speedup vs baseline: 11.0383x; 11.0383x over previous
//
#include <hip/hip_runtime.h>
#include <math.h>

// LSTM autoencoder, fp32 — kernel-chain design (R10/R11 resubmit).
// After R9's persistent-kernel abort: no custom barriers, no inline asm, no cache
// tricks. Kernel boundaries provide coherence. 1539 launches, graph-replayed:
//   encoder: 513 kernels (layer-skewed: kernel k = layer0(k) || layer1(k-1))
//   decoder: 1024 kernels (2/step; out-feedback forbids skewing)
// Block math (stage16/dot16/reduce16, 4x4 reg tile) is byte-compatible with the
// R2 kernel that PASSED correctness (absmax 3.05e-5) on MI355X.

#define B_     128
#define T_     512
#define H_     256
#define G_     1024
#define BB     16            // batches per block
#define NBC    8             // batch chunks
#define JJ     4             // hidden units per block
#define NHG    64            // hidden groups
#define NBPART (NBC*NHG)     // 512 blocks per layer-part
#define NTHR   256
#define BH     (B_*H_)

// ws float offsets (contiguous; init zeroes the first 6*BH)
#define WS_H0  0                     // [2][B][H]  h0 parity buffers
#define WS_H1  (WS_H0 + 2*BH)        // [2][B][H]  h1 parity buffers
#define WS_C0  (WS_H1 + 2*BH)        // [B][H]
#define WS_C1  (WS_C0 + BH)          // [B][H]
#define WS_EB  (WS_C1 + BH)          // [4][G] combined biases: enc0,enc1,dec0,dec1

__global__ void init_kernel(float* __restrict__ ws,
    const float* __restrict__ e0a, const float* __restrict__ e0b,
    const float* __restrict__ e1a, const float* __restrict__ e1b,
    const float* __restrict__ d0a, const float* __restrict__ d0b,
    const float* __restrict__ d1a, const float* __restrict__ d1b)
{
  int i = blockIdx.x*blockDim.x + threadIdx.x;
  int n = gridDim.x*blockDim.x;
  for (int k = i; k < 6*BH; k += n) ws[k] = 0.0f;       // h0[2], h1[2], c0, c1
  for (int k = i; k < G_; k += n) {
    ws[WS_EB + 0*G_ + k] = e0a[k] + e0b[k];
    ws[WS_EB + 1*G_ + k] = e1a[k] + e1b[k];
    ws[WS_EB + 2*G_ + k] = d0a[k] + d0b[k];
    ws[WS_EB + 3*G_ + k] = d1a[k] + d1b[k];
  }
}

__device__ __forceinline__ float sigm(float v) { return 1.0f/(1.0f + expf(-v)); }

// stage one 16-row x 256-col weight slice into LDS (rows q*H + j0 + jl), coalesced
__device__ __forceinline__ void stage16(float* dst, const float* __restrict__ W,
                                        int j0, int tid)
{
#pragma unroll
  for (int m = 0; m < 4; ++m) {
    int idx = tid + m*NTHR;             // float4 index 0..1023
    int r   = idx >> 6;                 // local row 0..15 (= q*4 + jl)
    int c4  = idx & 63;
    int grow = (r >> 2)*H_ + j0 + (r & 3);
    *(float4*)(dst + r*H_ + c4*4) = *(const float4*)(W + grow*H_ + c4*4);
  }
}

// stage a contiguous [16][256] h chunk into LDS
__device__ __forceinline__ void stage_h(float* dst, const float* __restrict__ src,
                                        int tid)
{
#pragma unroll
  for (int m = 0; m < 4; ++m) {
    int idx = (tid + m*NTHR)*4;
    *(float4*)(dst + idx) = *(const float4*)(src + idx);
  }
}

// r[i*4+q] += W[q*4+j] . h[bp*4+i] over this lane's K-sixteenth (R2-validated)
__device__ __forceinline__ void dot16(float r[16], const float* __restrict__ wlds,
                                      const float* __restrict__ hs,
                                      int j, int bp, int kq)
{
#pragma unroll
  for (int m = 0; m < 4; ++m) {
    const int ko = kq*4 + m*64;
    float4 hv[4], wv[4];
#pragma unroll
    for (int i = 0; i < 4; ++i) hv[i] = *(const float4*)&hs[(bp*4+i)*H_ + ko];
#pragma unroll
    for (int q = 0; q < 4; ++q) wv[q] = *(const float4*)&wlds[(q*4+j)*H_ + ko];
#pragma unroll
    for (int i = 0; i < 4; ++i)
#pragma unroll
      for (int q = 0; q < 4; ++q)
        r[i*4+q] += wv[q].x*hv[i].x + wv[q].y*hv[i].y
                  + wv[q].z*hv[i].z + wv[q].w*hv[i].w;
  }
}

// ownership-splitting butterfly: lane kq ends with r[0..3] = 4 gates of batch kq>>2
// (R2-validated)
__device__ __forceinline__ void reduce16(float r[16], int kq)
{
  {
    bool hi = (kq & 8) != 0;
#pragma unroll
    for (int v = 0; v < 8; ++v) {
      float keep = hi ? r[v+8] : r[v];
      float send = hi ? r[v] : r[v+8];
      r[v] = keep + __shfl_xor(send, 8);
    }
  }
  {
    bool hi = (kq & 4) != 0;
#pragma unroll
    for (int v = 0; v < 4; ++v) {
      float keep = hi ? r[v+4] : r[v];
      float send = hi ? r[v] : r[v+4];
      r[v] = keep + __shfl_xor(send, 4);
    }
  }
#pragma unroll
  for (int v = 0; v < 4; ++v) {
    r[v] += __shfl_xor(r[v], 2);
    r[v] += __shfl_xor(r[v], 1);
  }
}

// One pipeline phase. t0>=0: first 512 blocks run layer0(t0). t1>=0: next 512
// blocks run layer1(t1). Parities: h_layer(t) lives at parity t&1.
__global__ __launch_bounds__(NTHR) void step_kernel(
    float* __restrict__ ws, const float* __restrict__ x,
    const float* __restrict__ Wih0, const float* __restrict__ Whh0,
    const float* __restrict__ Wih1, const float* __restrict__ Whh1,
    const float* __restrict__ outW, const float* __restrict__ outB,
    float* __restrict__ dout, int t0, int t1, int dec)
{
  __shared__ __align__(16) float smem[16384];   // exactly 64 KB
  float* sW0  = smem;                            // [16][256]
  float* sW1  = smem + 4096;                     // [16][256] (layer1 only)
  float* sH0  = smem + 8192;                     // [16][256]
  float* sH1  = smem + 12288;                    // [16][256] (layer1 only)
  float* slds = smem + 4096;                     // aliases sW1 (layer0 only)

  const int nb0 = (t0 >= 0) ? NBPART : 0;
  const bool isL0 = (int)blockIdx.x < nb0;
  const int pb  = isL0 ? (int)blockIdx.x : (int)blockIdx.x - nb0;
  const int bc  = pb & (NBC-1);
  const int hg  = pb >> 3;
  const int tid = (int)threadIdx.x;
  const int kq = tid & 15, j = (tid >> 4) & 3, bp = tid >> 6;
  const int j0 = hg*JJ, bcb = bc*BB;
  const int b_own = bcb + bp*4 + (kq >> 2);

  float* h0buf = ws + WS_H0;
  float* h1buf = ws + WS_H1;
  float* c0g   = ws + WS_C0;
  float* c1g   = ws + WS_C1;
  const float* EB = ws + WS_EB;

  if (isL0) {
    // ---------------- layer0(t): h0(t) = cell(inp, h0(t-1), c0) ----------------
    const int t = t0;
    const int rp = (t-1) & 1, wp = t & 1;        // (-1)&1 == 1: zeros at start
    stage16(sW0, Whh0, j0, tid);
    stage_h(sH0, h0buf + rp*BH + bcb*H_, tid);

    float inp = 0.f;
    if (dec) {
      if (t == 0) {
        inp = x[b_own*T_];                       // init_inp = x[:,0]
      } else {
        // out(t-1) = outW . h1(t-1) + outb  (h1(t-1) @ parity rp, prev kernel)
        const int bo = tid >> 4, seg = tid & 15;
        const float* hp = h1buf + rp*BH + (bcb + bo)*H_ + seg*16;
        float p = 0.f;
#pragma unroll
        for (int u = 0; u < 4; ++u) {
          float4 hv = *(const float4*)(hp + u*4);
          float4 wv = *(const float4*)(outW + seg*16 + u*4);
          p += wv.x*hv.x + wv.y*hv.y + wv.z*hv.z + wv.w*hv.w;
        }
        p += __shfl_xor(p, 8); p += __shfl_xor(p, 4);
        p += __shfl_xor(p, 2); p += __shfl_xor(p, 1);
        if (seg == 0) {
          float o = p + outB[0];
          slds[bo] = o;
          if (hg == 0) dout[(bcb + bo)*T_ + (t-1)] = o;
        }
      }
    } else {
      inp = x[b_own*T_ + t];
    }
    __syncthreads();                             // stages + slds ready
    if (dec && t > 0) inp = slds[bp*4 + (kq >> 2)];

    float r[16];
#pragma unroll
    for (int v = 0; v < 16; ++v) r[v] = 0.f;
    dot16(r, sW0, sH0, j, bp, kq);
    reduce16(r, kq);

    if ((kq & 3) == 0) {
      const float* ebL = EB + (dec ? 2*G_ : 0);
      const int rr = j0 + j;
      float g0 = r[0] + ebL[0*H_+rr] + inp*Wih0[0*H_+rr];
      float g1 = r[1] + ebL[1*H_+rr] + inp*Wih0[1*H_+rr];
      float g2 = r[2] + ebL[2*H_+rr] + inp*Wih0[2*H_+rr];
      float g3 = r[3] + ebL[3*H_+rr] + inp*Wih0[3*H_+rr];
      float si = sigm(g0), sf = sigm(g1), tg = tanhf(g2), so = sigm(g3);
      float c = c0g[b_own*H_ + rr];
      c = sf*c + si*tg;
      c0g[b_own*H_ + rr] = c;
      h0buf[wp*BH + b_own*H_ + rr] = so*tanhf(c);
    }
  } else {
    // ------------- layer1(t): h1(t) = cell(h0(t), h1(t-1), c1) -------------
    const int t = t1;
    const int rp = (t-1) & 1, wp = t & 1;
    stage16(sW0, Wih1, j0, tid);
    stage16(sW1, Whh1, j0, tid);
    stage_h(sH0, h0buf + wp*BH + bcb*H_, tid);   // h0(t) @ parity t&1
    stage_h(sH1, h1buf + rp*BH + bcb*H_, tid);   // h1(t-1)
    __syncthreads();

    float r[16];
#pragma unroll
    for (int v = 0; v < 16; ++v) r[v] = 0.f;
    dot16(r, sW0, sH0, j, bp, kq);               // Wih1 . h0(t)
    dot16(r, sW1, sH1, j, bp, kq);               // Whh1 . h1(t-1)
    reduce16(r, kq);

    if ((kq & 3) == 0) {
      const float* ebL = EB + (dec ? 3*G_ : 1*G_);
      const int rr = j0 + j;
      float g0 = r[0] + ebL[0*H_+rr];
      float g1 = r[1] + ebL[1*H_+rr];
      float g2 = r[2] + ebL[2*H_+rr];
      float g3 = r[3] + ebL[3*H_+rr];
      float si = sigm(g0), sf = sigm(g1), tg = tanhf(g2), so = sigm(g3);
      float c = c1g[b_own*H_ + rr];
      c = sf*c + si*tg;
      c1g[b_own*H_ + rr] = c;
      h1buf[wp*BH + b_own*H_ + rr] = so*tanhf(c);
    }
  }
}

// out(T-1) = outW . h1(T-1) + outb  (h1(T-1) @ parity (T-1)&1 = 1)
__global__ void final_out_kernel(const float* __restrict__ ws,
    const float* __restrict__ outW, const float* __restrict__ outB,
    float* __restrict__ dout)
{
  int b = (int)threadIdx.x;
  if (b < B_) {
    const float* hp = ws + WS_H1 + ((T_-1) & 1)*BH + b*H_;
    float s = outB[0];
    for (int k = 0; k < H_; k += 4) {
      float4 h = *(const float4*)(hp + k);
      float4 w = *(const float4*)(outW + k);
      s += w.x*h.x + w.y*h.y + w.z*h.z + w.w*h.w;
    }
    dout[b*T_ + (T_-1)] = s;
  }
}

extern "C" void kernel_launch(void* const* d_in, const int* in_sizes, int n_in,
                              void* d_out, int out_size, void* d_ws, size_t ws_size,
                              hipStream_t stream)
{
  const float* x     = (const float*)d_in[0];
  const float* eWih0 = (const float*)d_in[1];
  const float* eWhh0 = (const float*)d_in[2];
  const float* ebih0 = (const float*)d_in[3];
  const float* ebhh0 = (const float*)d_in[4];
  const float* eWih1 = (const float*)d_in[5];
  const float* eWhh1 = (const float*)d_in[6];
  const float* ebih1 = (const float*)d_in[7];
  const float* ebhh1 = (const float*)d_in[8];
  const float* dWih0 = (const float*)d_in[9];
  const float* dWhh0 = (const float*)d_in[10];
  const float* dbih0 = (const float*)d_in[11];
  const float* dbhh0 = (const float*)d_in[12];
  const float* dWih1 = (const float*)d_in[13];
  const float* dWhh1 = (const float*)d_in[14];
  const float* dbih1 = (const float*)d_in[15];
  const float* dbhh1 = (const float*)d_in[16];
  const float* outW  = (const float*)d_in[17];
  const float* outB  = (const float*)d_in[18];
  float* out = (float*)d_out;
  float* ws  = (float*)d_ws;

  init_kernel<<<dim3(64), dim3(256), 0, stream>>>(ws, ebih0, ebhh0, ebih1, ebhh1,
                                                  dbih0, dbhh0, dbih1, dbhh1);

  // encoder: skewed pipeline, kernel k = layer0(k) || layer1(k-1)
  for (int k = 0; k <= T_; ++k) {
    int t0 = (k < T_) ? k : -1;
    int t1 = (k >= 1) ? k - 1 : -1;
    int grid = ((t0 >= 0) ? NBPART : 0) + ((t1 >= 0) ? NBPART : 0);
    step_kernel<<<dim3(grid), dim3(NTHR), 0, stream>>>(
        ws, x, eWih0, eWhh0, eWih1, eWhh1, outW, outB, out, t0, t1, 0);
  }

  // decoder: 2 kernels per step (out-feedback forbids skewing)
  for (int t = 0; t < T_; ++t) {
    step_kernel<<<dim3(NBPART), dim3(NTHR), 0, stream>>>(
        ws, x, dWih0, dWhh0, dWih1, dWhh1, outW, outB, out, t, -1, 1);
    step_kernel<<<dim3(NBPART), dim3(NTHR), 0, stream>>>(
        ws, x, dWih0, dWhh0, dWih1, dWhh1, outW, outB, out, -1, t, 1);
  }

  final_out_kernel<<<dim3(1), dim3(128), 0, stream>>>(ws, outW, outB, out);
}